// Round 15
// baseline (325.585 us; speedup 1.0000x reference)
//
#include <hip/hip_runtime.h>
#include <hip/hip_bf16.h>
#include <stdint.h>

#define K_DIM 4096
#define M_DIM 8192
#define N_DIM 4096

typedef short bf16x8 __attribute__((ext_vector_type(8)));
typedef float f32x4  __attribute__((ext_vector_type(4)));

__device__ __forceinline__ uint16_t f2bf(float f) {
  uint32_t u = __float_as_uint(f);
  u += 0x7fffu + ((u >> 16) & 1u);   // round-to-nearest-even
  return (uint16_t)(u >> 16);
}

__device__ __forceinline__ float wval(float b0, float b1, float b2, float sg) {
  float mg = (b0 >= 0.f ? 0.5f : 0.f) + (b1 >= 0.f ? 0.25f : 0.f) + (b2 >= 0.f ? 0.125f : 0.f);
  return (sg >= 0.f) ? mg : -mg;
}

__device__ __forceinline__ void gload16(const void* g, void* l) {
  typedef __attribute__((address_space(1))) const uint32_t gu32;
  typedef __attribute__((address_space(3))) uint32_t lu32;
  __builtin_amdgcn_global_load_lds((gu32*)g, (lu32*)l, 16, 0, 0);
}

// ---------- Kernel 1: FUSED prep — W^T build + x f32->bf16 cast ------------
// build_wt and cvt_x are data-independent and both HBM-bound; run them as one
// dispatch with interleaved block roles (2:1 = 4096 build : 2048 cvt) so both
// streams co-saturate HBM for the whole dispatch (two serial kernels each
// underfill BW and pay their own tail). bid%3 in {0,1} -> build tile
// (bid/3)*2 + (bid%3); bid%3==2 -> cvt chunk bid/3.
__global__ __launch_bounds__(256) void prep_fused(
    const float* __restrict__ mag, const float* __restrict__ sgn,
    uint16_t* __restrict__ wt, float* __restrict__ psum, float* __restrict__ psumsq,
    const float* __restrict__ x, uint16_t* __restrict__ xb)
{
  const int bid = blockIdx.x;
  const int r3  = bid % 3;
  const int q3  = bid / 3;
  const int tid = threadIdx.x;

  if (r3 == 2) {
    // ---- cvt_x role: chunk q3 of 2048, grid-stride 2048*256 over n8 ----
    const int n8 = (M_DIM * K_DIM) / 8;
    int idx = q3 * 256 + tid;
    const int stride = 2048 * 256;
    for (; idx < n8; idx += stride) {
      float4 v0 = ((const float4*)x)[2 * idx];
      float4 v1 = ((const float4*)x)[2 * idx + 1];
      ushort4 r0, r1;
      r0.x = f2bf(v0.x); r0.y = f2bf(v0.y); r0.z = f2bf(v0.z); r0.w = f2bf(v0.w);
      r1.x = f2bf(v1.x); r1.y = f2bf(v1.y); r1.z = f2bf(v1.z); r1.w = f2bf(v1.w);
      ((ushort4*)xb)[2 * idx]     = r0;
      ((ushort4*)xb)[2 * idx + 1] = r1;
    }
    return;
  }

  // ---- build_wt role: flat tile b in [0,4096): o-tile = b&63, i-tile = b>>6 ----
  const int b  = q3 * 2 + r3;
  __shared__ float wl[64][65];
  __shared__ float parts[8];
  const int lr = tid >> 4;   // 0..15
  const int lc = tid & 15;   // 0..15
  const int i0 = (b >> 6) * 64;   // input-dim (K) tile
  const int o0 = (b & 63) * 64;   // output-dim (N) tile
  const float* m0 = mag;
  const float* m1 = mag + (size_t)K_DIM * N_DIM;
  const float* m2 = mag + 2 * (size_t)K_DIM * N_DIM;

  float s = 0.f, s2 = 0.f;
  #pragma unroll
  for (int rg = 0; rg < 4; ++rg) {
    int il = rg * 16 + lr;
    size_t base = (size_t)(i0 + il) * N_DIM + o0 + lc * 4;
    float4 a = *(const float4*)(m0 + base);
    float4 bb = *(const float4*)(m1 + base);
    float4 c = *(const float4*)(m2 + base);
    float4 g = *(const float4*)(sgn + base);
    float w0 = wval(a.x, bb.x, c.x, g.x);
    float w1 = wval(a.y, bb.y, c.y, g.y);
    float w2 = wval(a.z, bb.z, c.z, g.z);
    float w3 = wval(a.w, bb.w, c.w, g.w);
    wl[il][lc * 4 + 0] = w0;
    wl[il][lc * 4 + 1] = w1;
    wl[il][lc * 4 + 2] = w2;
    wl[il][lc * 4 + 3] = w3;
    s  += w0 + w1 + w2 + w3;
    s2 += w0 * w0 + w1 * w1 + w2 * w2 + w3 * w3;
  }
  // deterministic per-block reduction (no float atomics -> replay-stable)
  #pragma unroll
  for (int off = 32; off > 0; off >>= 1) {
    s  += __shfl_down(s,  off);
    s2 += __shfl_down(s2, off);
  }
  if ((tid & 63) == 0) { parts[tid >> 6] = s; parts[4 + (tid >> 6)] = s2; }
  __syncthreads();
  if (tid == 0) {
    psum[b]   = parts[0] + parts[1] + parts[2] + parts[3];
    psumsq[b] = parts[4] + parts[5] + parts[6] + parts[7];
  }
  // transposed coalesced write: Wt[o][i]
  #pragma unroll
  for (int rg = 0; rg < 4; ++rg) {
    int ol = rg * 16 + lr;
    int il = lc * 4;
    ushort4 v;
    v.x = f2bf(wl[il + 0][ol]);
    v.y = f2bf(wl[il + 1][ol]);
    v.z = f2bf(wl[il + 2][ol]);
    v.w = f2bf(wl[il + 3][ol]);
    *(ushort4*)(wt + (size_t)(o0 + ol) * K_DIM + i0 + il) = v;
  }
}

// ---------- Kernel 3: alpha = std_target / (std(w) + eps) ----------
__global__ __launch_bounds__(256) void calc_alpha(const float* __restrict__ psum,
                                                  const float* __restrict__ psumsq,
                                                  float* __restrict__ alpha, int nparts)
{
  __shared__ float ls[256], lq[256];
  int tid = threadIdx.x;
  float s = 0.f, q = 0.f;
  for (int i = tid; i < nparts; i += 256) { s += psum[i]; q += psumsq[i]; }
  ls[tid] = s; lq[tid] = q;
  __syncthreads();
  for (int off = 128; off > 0; off >>= 1) {
    if (tid < off) { ls[tid] += ls[tid + off]; lq[tid] += lq[tid + off]; }
    __syncthreads();
  }
  if (tid == 0) {
    const float n = 16777216.f;
    float mean = ls[0] / n;
    float var  = lq[0] / n - mean * mean;
    var = var < 0.f ? 0.f : var;
    float stdv = sqrtf(var);
    alpha[0] = 0.022097086912079608f / (stdv + 1e-8f);  // sqrt(2/4096)/(std+eps)
  }
}

// ---------- Kernel 4: 256x256 bf16 GEMM (byte-identical to R14) ------------
// Read-ahead + 2 barriers/tile; register-diet addressing; zero-conflict
// swizzle; proofs in R13/R14 notes. 217us, ~1267 TF, absmax-stable.
__global__ __launch_bounds__(512, 2) void gemm_bf16_b2(
    const uint16_t* __restrict__ xb, const uint16_t* __restrict__ wt,
    const float* __restrict__ alphap, float* __restrict__ out)
{
  __shared__ __align__(16) unsigned char sLDS[131072];

  const int tid  = threadIdx.x;
  const int lane = tid & 63;
  const int wv   = tid >> 6;        // 0..7
  const int wm   = wv >> 2;         // 0..1
  const int wn   = wv & 3;          // 0..3

  // XCD-aware bijective swizzle: 512 blocks = 8 regions of 8x8
  const int bid = blockIdx.x;
  const int xcd = bid & 7;
  const int c   = bid >> 3;                  // 0..63
  const int bm  = (xcd >> 1) * 8 + (c >> 3); // 0..31
  const int bn  = (xcd & 1) * 8 + (c & 7);   // 0..15

  f32x4 acc[8][4] = {};

  const int l15 = lane & 15;
  // zero-conflict swizzle terms (verified R1/R3/R4): read cb = kcol ^ swz
  const int swz  = (lane & 7) << 4;
  const int kcol = (lane >> 4) << 4;
  // 4 invariant ds_read address VGPRs (all other selectors -> offset imms)
  const int rdA0 = (wm * 64 + l15) * 128 + (kcol ^ swz);
  const int rdA1 = rdA0 ^ 64;
  const int rdB0 = 65536 + (wn * 32 + l15) * 128 + (kcol ^ swz);
  const int rdB1 = rdB0 ^ 64;
  // staging: source pre-swizzle + per-lane offsets folded into base pointers
  const int src_x = ((lane & 7) ^ (lane >> 3)) << 4;
  const char* gA = (const char*)xb + ((size_t)bm * 256 * K_DIM) * 2
                   + (size_t)((wv * 8 + (lane >> 3)) * K_DIM) * 2 + src_x;
  const char* gB = (const char*)wt + ((size_t)bn * 256 * K_DIM) * 2
                   + (size_t)((((wv >> 2) * 64) + (wv & 3) * 8 + (lane >> 3)) * K_DIM) * 2 + src_x;

#define STA(cc_, mh, h, kt)                                                         \
  gload16(gA + ((size_t)(((h) * 128 + (mh) * 64) * K_DIM + (size_t)(kt) * 64) << 1), \
          sLDS + (cc_) * 32768 + ((mh) * 128 + (h) * 64 + wv * 8) * 128)
#define STB(cc_, bh, h, kt)                                                         \
  gload16(gB + ((size_t)(((h) * 128 + (bh) * 32) * K_DIM + (size_t)(kt) * 64) << 1), \
          sLDS + 65536 + (cc_) * 32768 + ((bh) * 128 + (h) * 64 + wv * 8) * 128)
#define STAGE_A(cc_, mh, kt) do { STA(cc_, mh, 0, kt); STA(cc_, mh, 1, kt); } while (0)
#define STAGE_B(cc_, bh, kt) do { STB(cc_, bh, 0, kt); STB(cc_, bh, 1, kt); } while (0)

#define LDA8(bufc, mh, dst) do { _Pragma("unroll")                                  \
  for (int m = 0; m < 4; ++m) {                                                     \
    dst[2 * m]     = *(const bf16x8*)(sLDS + (bufc) * 32768 + (mh) * 16384 + m * 2048 + rdA0); \
    dst[2 * m + 1] = *(const bf16x8*)(sLDS + (bufc) * 32768 + (mh) * 16384 + m * 2048 + rdA1); \
  } } while (0)
#define LDB4(bufc, bh, dst) do { _Pragma("unroll")                                  \
  for (int n = 0; n < 2; ++n) {                                                     \
    dst[2 * n]     = *(const bf16x8*)(sLDS + (bufc) * 32768 + (bh) * 16384 + n * 2048 + rdB0); \
    dst[2 * n + 1] = *(const bf16x8*)(sLDS + (bufc) * 32768 + (bh) * 16384 + n * 2048 + rdB1); \
  } } while (0)

// kk-outer: 8 independent MFMAs between dependent kk-pairs
#define MMQ(AF, BF, mh, bh) do {                                                    \
  __builtin_amdgcn_s_setprio(1);                                                    \
  _Pragma("unroll") for (int kk = 0; kk < 2; ++kk)                                  \
    _Pragma("unroll") for (int m = 0; m < 4; ++m)                                   \
      _Pragma("unroll") for (int n = 0; n < 2; ++n)                                 \
        acc[(mh)*4+m][(bh)*2+n] = __builtin_amdgcn_mfma_f32_16x16x32_bf16(          \
            AF[2*m+kk], BF[2*n+kk], acc[(mh)*4+m][(bh)*2+n], 0, 0, 0);              \
  __builtin_amdgcn_s_setprio(0); } while (0)

#define SCHED0   __builtin_amdgcn_sched_barrier(0)
#define LGKM0    do { asm volatile("s_waitcnt lgkmcnt(0)" ::: "memory"); SCHED0; } while (0)
#define WAITV(N) do { asm volatile("s_waitcnt vmcnt(" #N ")"   ::: "memory"); SCHED0; } while (0)
#define BAR      do { asm volatile("s_barrier" ::: "memory"); SCHED0; } while (0)

  bf16x8 A0f[8], A1f[8], B0f[4], B1f[4];

  // ---- prologue: stage tile0 {A0,B0,B1,A1} + tile1 {A0,B0,B1}; certify all ----
  STAGE_A(0, 0, 0); STAGE_B(0, 0, 0); STAGE_B(0, 1, 0); STAGE_A(0, 1, 0);
  STAGE_A(1, 0, 1); STAGE_B(1, 0, 1); STAGE_B(1, 1, 1);
  WAITV(0); BAR;
  LDA8(0, 0, A0f); LDB4(0, 0, B0f); SCHED0;   // tile0 A0,B0 (drain @p0 LGKM0)

  #pragma unroll 1
  for (int t = 0; t < 32; ++t) {
    const int k1 = 2 * t + 1;                          // <= 63 always
    const int k2 = (2 * t + 2 < 64) ? 2 * t + 2 : 63;  // clamped tail (junk, unused)
    const int k3 = (2 * t + 3 < 64) ? 2 * t + 3 : 63;

    // ===== tile u=2t from buf0 =====
    // p0: Q00(u)  [even, no barrier]
    STAGE_A(1, 1, k1);              // A1(v) -> buf1   (slot read p5(t-1), cert BAR(p7))
    LGKM0;
    LDB4(0, 1, B1f); SCHED0;        // read B1(u)
    MMQ(A0f, B0f, 0, 0);

    // p1: Q01(u)  [odd: BAR then STAGE]
    BAR;
    STAGE_A(0, 0, k2);              // A0(u+2) -> buf0 (slot read p6(t-1), cert BAR(p1))
    LGKM0;
    LDA8(0, 1, A1f); SCHED0;        // read A1(u)
    MMQ(A0f, B1f, 0, 1);

    // p2: Q10(u)  [even]
    STAGE_B(0, 0, k2);              // B0(u+2) -> buf0 (slot read p7(t-1), cert BAR(p1))
    LGKM0;
    LDA8(1, 0, A0f); SCHED0;        // read A0(v)
    MMQ(A1f, B0f, 1, 0);

    // p3: Q11(u)  [odd]
    WAITV(4);                       // retires stages {p6,p7(t-1),p0,p1}
    BAR;
    STAGE_B(0, 1, k2);              // B1(u+2) -> buf0 (slot read p0(t), cert BAR(p3))
    LGKM0;
    LDB4(1, 0, B0f); SCHED0;        // read B0(v) (staged p6(t-1): retired+published)
    MMQ(A1f, B1f, 1, 1);

    // ===== tile v=2t+1 from buf1 =====
    // p4: Q00(v)  [even]
    STAGE_A(0, 1, k2);              // A1(u+2) -> buf0 (slot read p1(t), cert BAR(p3))
    LGKM0;
    LDB4(1, 1, B1f); SCHED0;        // read B1(v) (staged p7(t-1): retired @p3)
    MMQ(A0f, B0f, 0, 0);

    // p5: Q01(v)  [odd]
    BAR;
    STAGE_A(1, 0, k3);              // A0(v+2) -> buf1 (slot read p2(t), cert BAR(p5))
    LGKM0;
    LDA8(1, 1, A1f); SCHED0;        // read A1(v) (staged p0: retired @p3)
    MMQ(A0f, B1f, 0, 1);

    // p6: Q10(v)  [even]
    STAGE_B(1, 0, k3);              // B0(v+2) -> buf1 (slot read p3(t), cert BAR(p5))
    LGKM0;
    LDA8(0, 0, A0f); SCHED0;        // read A0(u+2) (staged p1: retired @p3)
    MMQ(A1f, B0f, 1, 0);

    // p7: Q11(v)  [odd]
    WAITV(4);                       // retires stages {p2,p3,p4,p5}
    BAR;
    STAGE_B(1, 1, k3);              // B1(v+2) -> buf1 (slot read p4(t), cert BAR(p7))
    LGKM0;
    LDB4(0, 0, B0f); SCHED0;        // read B0(u+2) (staged p2: retired+published)
    MMQ(A1f, B1f, 1, 1);
  }

#undef STA
#undef STB
#undef STAGE_A
#undef STAGE_B
#undef LDA8
#undef LDB4
#undef MMQ
#undef SCHED0
#undef LGKM0
#undef WAITV
#undef BAR

  const float alpha = alphap[0];
  const int ccol  = bn * 256 + wn * 64 + l15;
  const int crow0 = bm * 256 + wm * 128 + ((lane >> 4) << 2);
  #pragma unroll
  for (int am = 0; am < 8; ++am)
    #pragma unroll
    for (int an = 0; an < 4; ++an)
      #pragma unroll
      for (int r = 0; r < 4; ++r)
        out[(size_t)(crow0 + am * 16 + r) * N_DIM + ccol + an * 16] = acc[am][an][r] * alpha;
}

extern "C" void kernel_launch(void* const* d_in, const int* in_sizes, int n_in,
                              void* d_out, int out_size, void* d_ws, size_t ws_size,
                              hipStream_t stream) {
  const float* x   = (const float*)d_in[0];
  const float* mag = (const float*)d_in[1];
  const float* sgn = (const float*)d_in[2];
  float* out = (float*)d_out;

  char* ws = (char*)d_ws;
  float* alpha    = (float*)ws;
  float* psum     = (float*)(ws + 256);
  float* psumsq   = (float*)(ws + 256 + 16384);
  uint16_t* wt    = (uint16_t*)(ws + 256 + 32768);
  uint16_t* xb    = (uint16_t*)(ws + 256 + 32768 + 33554432ull);
  size_t needed = 256 + 32768 + 33554432ull + 67108864ull;
  if (ws_size < needed) return;

  prep_fused<<<dim3(6144), 256, 0, stream>>>(mag, sgn, wt, psum, psumsq, x, xb);
  calc_alpha<<<dim3(1), 256, 0, stream>>>(psum, psumsq, alpha, 4096);
  gemm_bf16_b2<<<dim3(512), 512, 0, stream>>>(xb, wt, alpha, out);
}

// Round 16
// 313.080 us; speedup vs baseline: 1.0399x; 1.0399x over previous
//
#include <hip/hip_runtime.h>
#include <hip/hip_bf16.h>
#include <stdint.h>

#define K_DIM 4096
#define M_DIM 8192
#define N_DIM 4096

typedef short bf16x8 __attribute__((ext_vector_type(8)));
typedef float f32x4  __attribute__((ext_vector_type(4)));

__device__ __forceinline__ uint16_t f2bf(float f) {
  uint32_t u = __float_as_uint(f);
  u += 0x7fffu + ((u >> 16) & 1u);   // round-to-nearest-even
  return (uint16_t)(u >> 16);
}

__device__ __forceinline__ float wval(float b0, float b1, float b2, float sg) {
  float mg = (b0 >= 0.f ? 0.5f : 0.f) + (b1 >= 0.f ? 0.25f : 0.f) + (b2 >= 0.f ? 0.125f : 0.f);
  return (sg >= 0.f) ? mg : -mg;
}

__device__ __forceinline__ void gload16(const void* g, void* l) {
  typedef __attribute__((address_space(1))) const uint32_t gu32;
  typedef __attribute__((address_space(3))) uint32_t lu32;
  __builtin_amdgcn_global_load_lds((gu32*)g, (lu32*)l, 16, 0, 0);
}

// ---------- Kernel 1: W^T (bf16) build + transpose + per-block sum/sumsq ----
__global__ __launch_bounds__(256) void build_wt(
    const float* __restrict__ mag, const float* __restrict__ sgn,
    uint16_t* __restrict__ wt, float* __restrict__ psum, float* __restrict__ psumsq)
{
  __shared__ float wl[64][65];
  __shared__ float parts[8];
  const int tid = threadIdx.x;
  const int lr = tid >> 4;   // 0..15
  const int lc = tid & 15;   // 0..15
  const int i0 = blockIdx.y * 64;   // input-dim (K) tile
  const int o0 = blockIdx.x * 64;   // output-dim (N) tile
  const float* m0 = mag;
  const float* m1 = mag + (size_t)K_DIM * N_DIM;
  const float* m2 = mag + 2 * (size_t)K_DIM * N_DIM;

  float s = 0.f, s2 = 0.f;
  #pragma unroll
  for (int rg = 0; rg < 4; ++rg) {
    int il = rg * 16 + lr;
    size_t base = (size_t)(i0 + il) * N_DIM + o0 + lc * 4;
    float4 a = *(const float4*)(m0 + base);
    float4 b = *(const float4*)(m1 + base);
    float4 c = *(const float4*)(m2 + base);
    float4 g = *(const float4*)(sgn + base);
    float w0 = wval(a.x, b.x, c.x, g.x);
    float w1 = wval(a.y, b.y, c.y, g.y);
    float w2 = wval(a.z, b.z, c.z, g.z);
    float w3 = wval(a.w, b.w, c.w, g.w);
    wl[il][lc * 4 + 0] = w0;
    wl[il][lc * 4 + 1] = w1;
    wl[il][lc * 4 + 2] = w2;
    wl[il][lc * 4 + 3] = w3;
    s  += w0 + w1 + w2 + w3;
    s2 += w0 * w0 + w1 * w1 + w2 * w2 + w3 * w3;
  }
  // deterministic per-block reduction (no float atomics -> replay-stable)
  #pragma unroll
  for (int off = 32; off > 0; off >>= 1) {
    s  += __shfl_down(s,  off);
    s2 += __shfl_down(s2, off);
  }
  if ((tid & 63) == 0) { parts[tid >> 6] = s; parts[4 + (tid >> 6)] = s2; }
  __syncthreads();
  if (tid == 0) {
    int bid = blockIdx.y * gridDim.x + blockIdx.x;
    psum[bid]   = parts[0] + parts[1] + parts[2] + parts[3];
    psumsq[bid] = parts[4] + parts[5] + parts[6] + parts[7];
  }
  // transposed coalesced write: Wt[o][i]
  #pragma unroll
  for (int rg = 0; rg < 4; ++rg) {
    int ol = rg * 16 + lr;
    int il = lc * 4;
    ushort4 v;
    v.x = f2bf(wl[il + 0][ol]);
    v.y = f2bf(wl[il + 1][ol]);
    v.z = f2bf(wl[il + 2][ol]);
    v.w = f2bf(wl[il + 3][ol]);
    *(ushort4*)(wt + (size_t)(o0 + ol) * K_DIM + i0 + il) = v;
  }
}

// ---------- Kernel 2: x f32 -> bf16 (64 B/thread/iter) ----------
__global__ __launch_bounds__(256) void cvt_x(const float* __restrict__ x,
                                             uint16_t* __restrict__ xb, int n16)
{
  int idx = blockIdx.x * blockDim.x + threadIdx.x;
  int stride = gridDim.x * blockDim.x;
  for (; idx < n16; idx += stride) {
    #pragma unroll
    for (int j = 0; j < 4; ++j) {
      float4 v = ((const float4*)x)[4 * idx + j];
      ushort4 r;
      r.x = f2bf(v.x); r.y = f2bf(v.y); r.z = f2bf(v.z); r.w = f2bf(v.w);
      ((ushort4*)xb)[4 * idx + j] = r;
    }
  }
}

// ---------- Kernel 3: alpha = std_target / (std(w) + eps) ----------
__global__ __launch_bounds__(256) void calc_alpha(const float* __restrict__ psum,
                                                  const float* __restrict__ psumsq,
                                                  float* __restrict__ alpha, int nparts)
{
  __shared__ float ls[256], lq[256];
  int tid = threadIdx.x;
  float s = 0.f, q = 0.f;
  for (int i = tid; i < nparts; i += 256) { s += psum[i]; q += psumsq[i]; }
  ls[tid] = s; lq[tid] = q;
  __syncthreads();
  for (int off = 128; off > 0; off >>= 1) {
    if (tid < off) { ls[tid] += ls[tid + off]; lq[tid] += lq[tid + off]; }
    __syncthreads();
  }
  if (tid == 0) {
    const float n = 16777216.f;
    float mean = ls[0] / n;
    float var  = lq[0] / n - mean * mean;
    var = var < 0.f ? 0.f : var;
    float stdv = sqrtf(var);
    alpha[0] = 0.022097086912079608f / (stdv + 1e-8f);  // sqrt(2/4096)/(std+eps)
  }
}

// ---------- Kernel 4: 256x256 bf16 GEMM (byte-identical to R14) ------------
// Read-ahead + 2 barriers/tile; register-diet addressing; zero-conflict
// swizzle; proofs in R13/R14 notes. 217us, ~1267 TF, absmax-stable.
__global__ __launch_bounds__(512, 2) void gemm_bf16_b2(
    const uint16_t* __restrict__ xb, const uint16_t* __restrict__ wt,
    const float* __restrict__ alphap, float* __restrict__ out)
{
  __shared__ __align__(16) unsigned char sLDS[131072];

  const int tid  = threadIdx.x;
  const int lane = tid & 63;
  const int wv   = tid >> 6;        // 0..7
  const int wm   = wv >> 2;         // 0..1
  const int wn   = wv & 3;          // 0..3

  // XCD-aware bijective swizzle: 512 blocks = 8 regions of 8x8
  const int bid = blockIdx.x;
  const int xcd = bid & 7;
  const int c   = bid >> 3;                  // 0..63
  const int bm  = (xcd >> 1) * 8 + (c >> 3); // 0..31
  const int bn  = (xcd & 1) * 8 + (c & 7);   // 0..15

  f32x4 acc[8][4] = {};

  const int l15 = lane & 15;
  // zero-conflict swizzle terms (verified R1/R3/R4): read cb = kcol ^ swz
  const int swz  = (lane & 7) << 4;
  const int kcol = (lane >> 4) << 4;
  // 4 invariant ds_read address VGPRs (all other selectors -> offset imms)
  const int rdA0 = (wm * 64 + l15) * 128 + (kcol ^ swz);
  const int rdA1 = rdA0 ^ 64;
  const int rdB0 = 65536 + (wn * 32 + l15) * 128 + (kcol ^ swz);
  const int rdB1 = rdB0 ^ 64;
  // staging: source pre-swizzle + per-lane offsets folded into base pointers
  const int src_x = ((lane & 7) ^ (lane >> 3)) << 4;
  const char* gA = (const char*)xb + ((size_t)bm * 256 * K_DIM) * 2
                   + (size_t)((wv * 8 + (lane >> 3)) * K_DIM) * 2 + src_x;
  const char* gB = (const char*)wt + ((size_t)bn * 256 * K_DIM) * 2
                   + (size_t)((((wv >> 2) * 64) + (wv & 3) * 8 + (lane >> 3)) * K_DIM) * 2 + src_x;

#define STA(cc_, mh, h, kt)                                                         \
  gload16(gA + ((size_t)(((h) * 128 + (mh) * 64) * K_DIM + (size_t)(kt) * 64) << 1), \
          sLDS + (cc_) * 32768 + ((mh) * 128 + (h) * 64 + wv * 8) * 128)
#define STB(cc_, bh, h, kt)                                                         \
  gload16(gB + ((size_t)(((h) * 128 + (bh) * 32) * K_DIM + (size_t)(kt) * 64) << 1), \
          sLDS + 65536 + (cc_) * 32768 + ((bh) * 128 + (h) * 64 + wv * 8) * 128)
#define STAGE_A(cc_, mh, kt) do { STA(cc_, mh, 0, kt); STA(cc_, mh, 1, kt); } while (0)
#define STAGE_B(cc_, bh, kt) do { STB(cc_, bh, 0, kt); STB(cc_, bh, 1, kt); } while (0)

#define LDA8(bufc, mh, dst) do { _Pragma("unroll")                                  \
  for (int m = 0; m < 4; ++m) {                                                     \
    dst[2 * m]     = *(const bf16x8*)(sLDS + (bufc) * 32768 + (mh) * 16384 + m * 2048 + rdA0); \
    dst[2 * m + 1] = *(const bf16x8*)(sLDS + (bufc) * 32768 + (mh) * 16384 + m * 2048 + rdA1); \
  } } while (0)
#define LDB4(bufc, bh, dst) do { _Pragma("unroll")                                  \
  for (int n = 0; n < 2; ++n) {                                                     \
    dst[2 * n]     = *(const bf16x8*)(sLDS + (bufc) * 32768 + (bh) * 16384 + n * 2048 + rdB0); \
    dst[2 * n + 1] = *(const bf16x8*)(sLDS + (bufc) * 32768 + (bh) * 16384 + n * 2048 + rdB1); \
  } } while (0)

// kk-outer: 8 independent MFMAs between dependent kk-pairs
#define MMQ(AF, BF, mh, bh) do {                                                    \
  __builtin_amdgcn_s_setprio(1);                                                    \
  _Pragma("unroll") for (int kk = 0; kk < 2; ++kk)                                  \
    _Pragma("unroll") for (int m = 0; m < 4; ++m)                                   \
      _Pragma("unroll") for (int n = 0; n < 2; ++n)                                 \
        acc[(mh)*4+m][(bh)*2+n] = __builtin_amdgcn_mfma_f32_16x16x32_bf16(          \
            AF[2*m+kk], BF[2*n+kk], acc[(mh)*4+m][(bh)*2+n], 0, 0, 0);              \
  __builtin_amdgcn_s_setprio(0); } while (0)

#define SCHED0   __builtin_amdgcn_sched_barrier(0)
#define LGKM0    do { asm volatile("s_waitcnt lgkmcnt(0)" ::: "memory"); SCHED0; } while (0)
#define WAITV(N) do { asm volatile("s_waitcnt vmcnt(" #N ")"   ::: "memory"); SCHED0; } while (0)
#define BAR      do { asm volatile("s_barrier" ::: "memory"); SCHED0; } while (0)

  bf16x8 A0f[8], A1f[8], B0f[4], B1f[4];

  // ---- prologue: stage tile0 {A0,B0,B1,A1} + tile1 {A0,B0,B1}; certify all ----
  STAGE_A(0, 0, 0); STAGE_B(0, 0, 0); STAGE_B(0, 1, 0); STAGE_A(0, 1, 0);
  STAGE_A(1, 0, 1); STAGE_B(1, 0, 1); STAGE_B(1, 1, 1);
  WAITV(0); BAR;
  LDA8(0, 0, A0f); LDB4(0, 0, B0f); SCHED0;   // tile0 A0,B0 (drain @p0 LGKM0)

  #pragma unroll 1
  for (int t = 0; t < 32; ++t) {
    const int k1 = 2 * t + 1;                          // <= 63 always
    const int k2 = (2 * t + 2 < 64) ? 2 * t + 2 : 63;  // clamped tail (junk, unused)
    const int k3 = (2 * t + 3 < 64) ? 2 * t + 3 : 63;

    // ===== tile u=2t from buf0 =====
    // p0: Q00(u)  [even, no barrier]
    STAGE_A(1, 1, k1);              // A1(v) -> buf1   (slot read p5(t-1), cert BAR(p7))
    LGKM0;
    LDB4(0, 1, B1f); SCHED0;        // read B1(u)
    MMQ(A0f, B0f, 0, 0);

    // p1: Q01(u)  [odd: BAR then STAGE]
    BAR;
    STAGE_A(0, 0, k2);              // A0(u+2) -> buf0 (slot read p6(t-1), cert BAR(p1))
    LGKM0;
    LDA8(0, 1, A1f); SCHED0;        // read A1(u)
    MMQ(A0f, B1f, 0, 1);

    // p2: Q10(u)  [even]
    STAGE_B(0, 0, k2);              // B0(u+2) -> buf0 (slot read p7(t-1), cert BAR(p1))
    LGKM0;
    LDA8(1, 0, A0f); SCHED0;        // read A0(v)
    MMQ(A1f, B0f, 1, 0);

    // p3: Q11(u)  [odd]
    WAITV(4);                       // retires stages {p6,p7(t-1),p0,p1}
    BAR;
    STAGE_B(0, 1, k2);              // B1(u+2) -> buf0 (slot read p0(t), cert BAR(p3))
    LGKM0;
    LDB4(1, 0, B0f); SCHED0;        // read B0(v) (staged p6(t-1): retired+published)
    MMQ(A1f, B1f, 1, 1);

    // ===== tile v=2t+1 from buf1 =====
    // p4: Q00(v)  [even]
    STAGE_A(0, 1, k2);              // A1(u+2) -> buf0 (slot read p1(t), cert BAR(p3))
    LGKM0;
    LDB4(1, 1, B1f); SCHED0;        // read B1(v) (staged p7(t-1): retired @p3)
    MMQ(A0f, B0f, 0, 0);

    // p5: Q01(v)  [odd]
    BAR;
    STAGE_A(1, 0, k3);              // A0(v+2) -> buf1 (slot read p2(t), cert BAR(p5))
    LGKM0;
    LDA8(1, 1, A1f); SCHED0;        // read A1(v) (staged p0: retired @p3)
    MMQ(A0f, B1f, 0, 1);

    // p6: Q10(v)  [even]
    STAGE_B(1, 0, k3);              // B0(v+2) -> buf1 (slot read p3(t), cert BAR(p5))
    LGKM0;
    LDA8(0, 0, A0f); SCHED0;        // read A0(u+2) (staged p1: retired @p3)
    MMQ(A1f, B0f, 1, 0);

    // p7: Q11(v)  [odd]
    WAITV(4);                       // retires stages {p2,p3,p4,p5}
    BAR;
    STAGE_B(1, 1, k3);              // B1(v+2) -> buf1 (slot read p4(t), cert BAR(p7))
    LGKM0;
    LDB4(0, 0, B0f); SCHED0;        // read B0(u+2) (staged p2: retired+published)
    MMQ(A1f, B1f, 1, 1);
  }

#undef STA
#undef STB
#undef STAGE_A
#undef STAGE_B
#undef LDA8
#undef LDB4
#undef MMQ
#undef SCHED0
#undef LGKM0
#undef WAITV
#undef BAR

  const float alpha = alphap[0];
  const int ccol  = bn * 256 + wn * 64 + l15;
  const int crow0 = bm * 256 + wm * 128 + ((lane >> 4) << 2);
  #pragma unroll
  for (int am = 0; am < 8; ++am)
    #pragma unroll
    for (int an = 0; an < 4; ++an)
      #pragma unroll
      for (int r = 0; r < 4; ++r)
        out[(size_t)(crow0 + am * 16 + r) * N_DIM + ccol + an * 16] = acc[am][an][r] * alpha;
}

extern "C" void kernel_launch(void* const* d_in, const int* in_sizes, int n_in,
                              void* d_out, int out_size, void* d_ws, size_t ws_size,
                              hipStream_t stream) {
  const float* x   = (const float*)d_in[0];
  const float* mag = (const float*)d_in[1];
  const float* sgn = (const float*)d_in[2];
  float* out = (float*)d_out;

  char* ws = (char*)d_ws;
  float* alpha    = (float*)ws;
  float* psum     = (float*)(ws + 256);
  float* psumsq   = (float*)(ws + 256 + 16384);
  uint16_t* wt    = (uint16_t*)(ws + 256 + 32768);
  uint16_t* xb    = (uint16_t*)(ws + 256 + 32768 + 33554432ull);
  size_t needed = 256 + 32768 + 33554432ull + 67108864ull;
  if (ws_size < needed) return;

  build_wt<<<dim3(64, 64), 256, 0, stream>>>(mag, sgn, wt, psum, psumsq);
  cvt_x<<<dim3(2048), 256, 0, stream>>>(x, xb, (M_DIM * K_DIM) / 16);
  calc_alpha<<<dim3(1), 256, 0, stream>>>(psum, psumsq, alpha, 4096);
  gemm_bf16_b2<<<dim3(512), 512, 0, stream>>>(xb, wt, alpha, out);
}